// Round 1
// baseline (52.379 us; speedup 1.0000x reference)
//
#include <hip/hip_runtime.h>

// RoiPoolingConv: crop-and-resize bilinear, img (1,64,64,1024) f32, 512 ROIs,
// 7x7 pool -> out (1,512,7,7,1024) f32.
//
// One block per (roi, py, px): 512*49 = 25088 blocks, 256 threads.
// Each thread owns 4 consecutive channels (one float4): 4 gather loads + 1 store,
// all coalesced along the channel (innermost, contiguous) dimension.

#define POOLSZ 7
#define NROIS  512
#define IMG_H  64
#define IMG_W  64
#define IMG_C  1024

__global__ __launch_bounds__(256) void roi_pool_kernel(
    const float* __restrict__ img,
    const int*   __restrict__ rois,
    float*       __restrict__ out)
{
    const int bid = blockIdx.x;
    const int r  = bid / (POOLSZ * POOLSZ);
    const int p  = bid % (POOLSZ * POOLSZ);
    const int py = p / POOLSZ;
    const int px = p % POOLSZ;

    // ROI box (wave-uniform; compiler scalarizes these loads)
    const int x1 = rois[r * 4 + 0];
    const int y1 = rois[r * 4 + 1];
    const int w  = rois[r * 4 + 2];
    const int h  = rois[r * 4 + 3];

    const int we = min(x1 + w, IMG_W) - x1;
    const int he = min(y1 + h, IMG_H) - y1;
    const float wef = (float)we;
    const float hef = (float)he;

    // Exactly the reference arithmetic: t = (p+0.5)*eff/POOL - 0.5
    const float ty  = (py + 0.5f) * hef / (float)POOLSZ - 0.5f;
    const float fy0 = floorf(ty);
    const float fy  = ty - fy0;
    const int yi0 = (int)fminf(fmaxf(fy0,        0.0f), hef - 1.0f) + y1;
    const int yi1 = (int)fminf(fmaxf(fy0 + 1.0f, 0.0f), hef - 1.0f) + y1;

    const float tx  = (px + 0.5f) * wef / (float)POOLSZ - 0.5f;
    const float fx0 = floorf(tx);
    const float fx  = tx - fx0;
    const int xi0 = (int)fminf(fmaxf(fx0,        0.0f), wef - 1.0f) + x1;
    const int xi1 = (int)fminf(fmaxf(fx0 + 1.0f, 0.0f), wef - 1.0f) + x1;

    const int c = threadIdx.x * 4;  // 256 threads * 4 ch = 1024 channels

    const size_t base00 = ((size_t)(yi0 * IMG_W + xi0)) * IMG_C + c;
    const size_t base01 = ((size_t)(yi0 * IMG_W + xi1)) * IMG_C + c;
    const size_t base10 = ((size_t)(yi1 * IMG_W + xi0)) * IMG_C + c;
    const size_t base11 = ((size_t)(yi1 * IMG_W + xi1)) * IMG_C + c;

    const float4 v00 = *reinterpret_cast<const float4*>(img + base00);
    const float4 v01 = *reinterpret_cast<const float4*>(img + base01);
    const float4 v10 = *reinterpret_cast<const float4*>(img + base10);
    const float4 v11 = *reinterpret_cast<const float4*>(img + base11);

    float4 o;
    {
        float top, bot;
        top = v00.x + (v01.x - v00.x) * fx;
        bot = v10.x + (v11.x - v10.x) * fx;
        o.x = top + (bot - top) * fy;
        top = v00.y + (v01.y - v00.y) * fx;
        bot = v10.y + (v11.y - v10.y) * fx;
        o.y = top + (bot - top) * fy;
        top = v00.z + (v01.z - v00.z) * fx;
        bot = v10.z + (v11.z - v10.z) * fx;
        o.z = top + (bot - top) * fy;
        top = v00.w + (v01.w - v00.w) * fx;
        bot = v10.w + (v11.w - v10.w) * fx;
        o.w = top + (bot - top) * fy;
    }

    const size_t obase = ((size_t)bid) * IMG_C + c;
    *reinterpret_cast<float4*>(out + obase) = o;
}

extern "C" void kernel_launch(void* const* d_in, const int* in_sizes, int n_in,
                              void* d_out, int out_size, void* d_ws, size_t ws_size,
                              hipStream_t stream) {
    const float* img  = (const float*)d_in[0];
    const int*   rois = (const int*)d_in[1];
    float*       out  = (float*)d_out;

    const int nblocks = NROIS * POOLSZ * POOLSZ;  // 25088
    roi_pool_kernel<<<nblocks, 256, 0, stream>>>(img, rois, out);
}

// Round 2
// 27.630 us; speedup vs baseline: 1.8957x; 1.8957x over previous
//
#include <hip/hip_runtime.h>

// RoiPoolingConv: crop-and-resize bilinear, img (1,64,64,1024) f32, 512 ROIs,
// 7x7 pool -> out (1,512,7,7,1024) f32.
//
// Channel-slab decomposition: 8 slabs x 128 channels. slab = blockIdx % 8 so
// (under round-robin block->XCD dispatch) each XCD only reads its 2 MB slab
// of the image -> resident in the 4 MB per-XCD L2 -> all gather re-reads are
// L2 hits. Output is streamed with nontemporal stores so the 12.8 MB/XCD
// write stream doesn't evict the slab.
//
// Block = one (roi, slab): 256 threads = 8 groups x 32 lanes.
// Each group handles one pool cell per iteration (32 lanes x float4 = 128 ch).

#define POOLSZ 7
#define NROIS  512
#define IMG_H  64
#define IMG_W  64
#define IMG_C  1024
#define NSLAB  8
#define SLABC  (IMG_C / NSLAB)   // 128 channels
#define CELLS  (POOLSZ * POOLSZ) // 49

typedef float fvec4 __attribute__((ext_vector_type(4)));

__global__ __launch_bounds__(256) void roi_pool_slab_kernel(
    const float* __restrict__ img,
    const int*   __restrict__ rois,
    float*       __restrict__ out)
{
    const int bid  = blockIdx.x;
    const int slab = bid & (NSLAB - 1);   // pin slab to XCD (round-robin heuristic)
    const int r    = bid >> 3;            // ROI index 0..511

    // ROI box (block-uniform -> scalar loads)
    const int x1 = rois[r * 4 + 0];
    const int y1 = rois[r * 4 + 1];
    const int w  = rois[r * 4 + 2];
    const int h  = rois[r * 4 + 3];

    const int we = min(x1 + w, IMG_W) - x1;
    const int he = min(y1 + h, IMG_H) - y1;
    const float wef = (float)we;
    const float hef = (float)he;

    const int g    = threadIdx.x >> 5;    // group 0..7 (one cell each)
    const int lane = threadIdx.x & 31;    // 0..31
    const int c    = slab * SLABC + lane * 4;

    #pragma unroll
    for (int iter = 0; iter < 7; ++iter) {
        const int cell = iter * 8 + g;
        if (cell < CELLS) {
            const int py = cell / POOLSZ;
            const int px = cell % POOLSZ;

            // Exactly the reference arithmetic: t = (p+0.5)*eff/POOL - 0.5
            const float ty  = (py + 0.5f) * hef / (float)POOLSZ - 0.5f;
            const float fy0 = floorf(ty);
            const float fy  = ty - fy0;
            const int yi0 = (int)fminf(fmaxf(fy0,        0.0f), hef - 1.0f) + y1;
            const int yi1 = (int)fminf(fmaxf(fy0 + 1.0f, 0.0f), hef - 1.0f) + y1;

            const float tx  = (px + 0.5f) * wef / (float)POOLSZ - 0.5f;
            const float fx0 = floorf(tx);
            const float fx  = tx - fx0;
            const int xi0 = (int)fminf(fmaxf(fx0,        0.0f), wef - 1.0f) + x1;
            const int xi1 = (int)fminf(fmaxf(fx0 + 1.0f, 0.0f), wef - 1.0f) + x1;

            const size_t base00 = ((size_t)(yi0 * IMG_W + xi0)) * IMG_C + c;
            const size_t base01 = ((size_t)(yi0 * IMG_W + xi1)) * IMG_C + c;
            const size_t base10 = ((size_t)(yi1 * IMG_W + xi0)) * IMG_C + c;
            const size_t base11 = ((size_t)(yi1 * IMG_W + xi1)) * IMG_C + c;

            const fvec4 v00 = *reinterpret_cast<const fvec4*>(img + base00);
            const fvec4 v01 = *reinterpret_cast<const fvec4*>(img + base01);
            const fvec4 v10 = *reinterpret_cast<const fvec4*>(img + base10);
            const fvec4 v11 = *reinterpret_cast<const fvec4*>(img + base11);

            const fvec4 top = v00 + (v01 - v00) * fx;
            const fvec4 bot = v10 + (v11 - v10) * fx;
            const fvec4 o   = top + (bot - top) * fy;

            const size_t obase = ((size_t)(r * CELLS + cell)) * IMG_C + c;
            __builtin_nontemporal_store(o, reinterpret_cast<fvec4*>(out + obase));
        }
    }
}

extern "C" void kernel_launch(void* const* d_in, const int* in_sizes, int n_in,
                              void* d_out, int out_size, void* d_ws, size_t ws_size,
                              hipStream_t stream) {
    const float* img  = (const float*)d_in[0];
    const int*   rois = (const int*)d_in[1];
    float*       out  = (float*)d_out;

    const int nblocks = NROIS * NSLAB;  // 4096 blocks, 256 threads each
    roi_pool_slab_kernel<<<nblocks, 256, 0, stream>>>(img, rois, out);
}

// Round 3
// 27.049 us; speedup vs baseline: 1.9365x; 1.0215x over previous
//
#include <hip/hip_runtime.h>

// RoiPoolingConv: crop-and-resize bilinear, img (1,64,64,1024) f32, 512 ROIs,
// 7x7 pool -> out (1,512,7,7,1024) f32.
//
// Channel-slab decomposition: 8 slabs x 128 channels, slab = blockIdx & 7 so
// under round-robin block->XCD dispatch each XCD only reads its 2 MB image
// slab -> L2-resident. NT stores keep the 12.8 MB/XCD write stream from
// evicting the slab.
//
// Block = 4 ROIs x 1 slab (grid 1024, 256 threads): flat float4-unit mapping
// (4*49*32 = 6272 units, 25 iters, ~2% tail waste vs 14% before). Per-ROI
// bilinear coords precomputed once into a small LDS table.

#define POOLSZ 7
#define NROIS  512
#define IMG_H  64
#define IMG_W  64
#define IMG_C  1024
#define NSLAB  8
#define SLABC  (IMG_C / NSLAB)     // 128
#define CELLS  (POOLSZ * POOLSZ)   // 49
#define RPB    4                   // ROIs per block
#define UNITS  (RPB * CELLS * 32)  // 6272 float4 units per block
#define ITERS  ((UNITS + 255) / 256) // 25

typedef float fvec4 __attribute__((ext_vector_type(4)));

__global__ __launch_bounds__(256) void roi_pool_kernel(
    const float* __restrict__ img,
    const int*   __restrict__ rois,
    float*       __restrict__ out)
{
    __shared__ int   sYi0[RPB][POOLSZ], sYi1[RPB][POOLSZ];
    __shared__ float sFy [RPB][POOLSZ];
    __shared__ int   sXi0[RPB][POOLSZ], sXi1[RPB][POOLSZ];
    __shared__ float sFx [RPB][POOLSZ];

    const int bid     = blockIdx.x;
    const int slab    = bid & (NSLAB - 1);     // pins slab to XCD (round-robin)
    const int roibase = (bid >> 3) * RPB;

    const int t = threadIdx.x;

    // --- setup: 56 threads compute the per-ROI, per-axis coord triples ---
    if (t < RPB * 2 * POOLSZ) {
        const int rl   = t / (2 * POOLSZ);
        const int j    = t % (2 * POOLSZ);
        const int axis = j / POOLSZ;            // 0 = y, 1 = x
        const int p    = j % POOLSZ;
        const int r    = roibase + rl;

        const int x1 = rois[r * 4 + 0];
        const int y1 = rois[r * 4 + 1];
        const int w  = rois[r * 4 + 2];
        const int h  = rois[r * 4 + 3];

        const int start = axis ? x1 : y1;
        const int lim   = axis ? IMG_W : IMG_H;
        const int ext   = axis ? w : h;
        const int eff   = min(start + ext, lim) - start;
        const float efff = (float)eff;

        // Exactly the reference arithmetic: t = (p+0.5)*eff/POOL - 0.5
        const float tq = (p + 0.5f) * efff / (float)POOLSZ - 0.5f;
        const float f0 = floorf(tq);
        const float fr = tq - f0;
        const int i0 = (int)fminf(fmaxf(f0,        0.0f), efff - 1.0f) + start;
        const int i1 = (int)fminf(fmaxf(f0 + 1.0f, 0.0f), efff - 1.0f) + start;

        if (axis == 0) { sYi0[rl][p] = i0; sYi1[rl][p] = i1; sFy[rl][p] = fr; }
        else           { sXi0[rl][p] = i0; sXi1[rl][p] = i1; sFx[rl][p] = fr; }
    }
    __syncthreads();

    // --- main loop: flat float4-unit mapping, 25 iterations ---
    #pragma unroll 5
    for (int it = 0; it < ITERS; ++it) {
        const int unit = it * 256 + t;
        if (unit < UNITS) {
            const int cellg = unit >> 5;          // 0..195
            const int lane  = unit & 31;          // float4 within 128-ch slab
            const int rl    = cellg / CELLS;      // 0..3
            const int cell  = cellg - rl * CELLS; // 0..48
            const int py    = cell / POOLSZ;
            const int px    = cell - py * POOLSZ;

            const int   yi0 = sYi0[rl][py];
            const int   yi1 = sYi1[rl][py];
            const float fy  = sFy [rl][py];
            const int   xi0 = sXi0[rl][px];
            const int   xi1 = sXi1[rl][px];
            const float fx  = sFx [rl][px];

            const int c = slab * SLABC + lane * 4;

            const size_t base00 = ((size_t)(yi0 * IMG_W + xi0)) * IMG_C + c;
            const size_t base01 = ((size_t)(yi0 * IMG_W + xi1)) * IMG_C + c;
            const size_t base10 = ((size_t)(yi1 * IMG_W + xi0)) * IMG_C + c;
            const size_t base11 = ((size_t)(yi1 * IMG_W + xi1)) * IMG_C + c;

            const fvec4 v00 = *reinterpret_cast<const fvec4*>(img + base00);
            const fvec4 v01 = *reinterpret_cast<const fvec4*>(img + base01);
            const fvec4 v10 = *reinterpret_cast<const fvec4*>(img + base10);
            const fvec4 v11 = *reinterpret_cast<const fvec4*>(img + base11);

            const fvec4 top = v00 + (v01 - v00) * fx;
            const fvec4 bot = v10 + (v11 - v10) * fx;
            const fvec4 o   = top + (bot - top) * fy;

            const int r = roibase + rl;
            const size_t obase = ((size_t)(r * CELLS + cell)) * IMG_C + c;
            __builtin_nontemporal_store(o, reinterpret_cast<fvec4*>(out + obase));
        }
    }
}

extern "C" void kernel_launch(void* const* d_in, const int* in_sizes, int n_in,
                              void* d_out, int out_size, void* d_ws, size_t ws_size,
                              hipStream_t stream) {
    const float* img  = (const float*)d_in[0];
    const int*   rois = (const int*)d_in[1];
    float*       out  = (float*)d_out;

    const int nblocks = (NROIS / RPB) * NSLAB;  // 1024 blocks, 256 threads
    roi_pool_kernel<<<nblocks, 256, 0, stream>>>(img, rois, out);
}

// Round 4
// 25.569 us; speedup vs baseline: 2.0485x; 1.0579x over previous
//
#include <hip/hip_runtime.h>

// RoiPoolingConv: crop-and-resize bilinear, img (1,64,64,1024) f32, 512 ROIs,
// 7x7 pool -> out (1,512,7,7,1024) f32.
//
// Channel-slab decomposition: 8 slabs x 128 channels, slab = blockIdx & 7 so
// under round-robin block->XCD dispatch each XCD only reads its 2 MB image
// slab -> L2-resident. NT stores keep the write stream from evicting the slab.
//
// R3 change: RPB 4 -> 2 (2048 blocks, 8 blocks/CU = 32 waves/CU, the max) to
// overlap L2-gather latency of some waves with the HBM write stream of others.

#define POOLSZ 7
#define NROIS  512
#define IMG_H  64
#define IMG_W  64
#define IMG_C  1024
#define NSLAB  8
#define SLABC  (IMG_C / NSLAB)     // 128
#define CELLS  (POOLSZ * POOLSZ)   // 49
#define RPB    2                   // ROIs per block
#define UNITS  (RPB * CELLS * 32)  // 3136 float4 units per block
#define ITERS  ((UNITS + 255) / 256) // 13

typedef float fvec4 __attribute__((ext_vector_type(4)));

__global__ __launch_bounds__(256, 8) void roi_pool_kernel(
    const float* __restrict__ img,
    const int*   __restrict__ rois,
    float*       __restrict__ out)
{
    __shared__ int   sYi0[RPB][POOLSZ], sYi1[RPB][POOLSZ];
    __shared__ float sFy [RPB][POOLSZ];
    __shared__ int   sXi0[RPB][POOLSZ], sXi1[RPB][POOLSZ];
    __shared__ float sFx [RPB][POOLSZ];

    const int bid     = blockIdx.x;
    const int slab    = bid & (NSLAB - 1);     // pins slab to XCD (round-robin)
    const int roibase = (bid >> 3) * RPB;

    const int t = threadIdx.x;

    // --- setup: 28 threads compute the per-ROI, per-axis coord triples ---
    if (t < RPB * 2 * POOLSZ) {
        const int rl   = t / (2 * POOLSZ);
        const int j    = t % (2 * POOLSZ);
        const int axis = j / POOLSZ;            // 0 = y, 1 = x
        const int p    = j % POOLSZ;
        const int r    = roibase + rl;

        const int x1 = rois[r * 4 + 0];
        const int y1 = rois[r * 4 + 1];
        const int w  = rois[r * 4 + 2];
        const int h  = rois[r * 4 + 3];

        const int start = axis ? x1 : y1;
        const int lim   = axis ? IMG_W : IMG_H;
        const int ext   = axis ? w : h;
        const int eff   = min(start + ext, lim) - start;
        const float efff = (float)eff;

        // Exactly the reference arithmetic: t = (p+0.5)*eff/POOL - 0.5
        const float tq = (p + 0.5f) * efff / (float)POOLSZ - 0.5f;
        const float f0 = floorf(tq);
        const float fr = tq - f0;
        const int i0 = (int)fminf(fmaxf(f0,        0.0f), efff - 1.0f) + start;
        const int i1 = (int)fminf(fmaxf(f0 + 1.0f, 0.0f), efff - 1.0f) + start;

        if (axis == 0) { sYi0[rl][p] = i0; sYi1[rl][p] = i1; sFy[rl][p] = fr; }
        else           { sXi0[rl][p] = i0; sXi1[rl][p] = i1; sFx[rl][p] = fr; }
    }
    __syncthreads();

    // --- main loop: flat float4-unit mapping, 13 iterations ---
    #pragma unroll
    for (int it = 0; it < ITERS; ++it) {
        const int unit = it * 256 + t;
        if (unit < UNITS) {
            const int cellg = unit >> 5;          // 0..97
            const int lane  = unit & 31;          // float4 within 128-ch slab
            const int rl    = cellg / CELLS;      // 0..1
            const int cell  = cellg - rl * CELLS; // 0..48
            const int py    = cell / POOLSZ;
            const int px    = cell - py * POOLSZ;

            const int   yi0 = sYi0[rl][py];
            const int   yi1 = sYi1[rl][py];
            const float fy  = sFy [rl][py];
            const int   xi0 = sXi0[rl][px];
            const int   xi1 = sXi1[rl][px];
            const float fx  = sFx [rl][px];

            const int c = slab * SLABC + lane * 4;

            const size_t base00 = ((size_t)(yi0 * IMG_W + xi0)) * IMG_C + c;
            const size_t base01 = ((size_t)(yi0 * IMG_W + xi1)) * IMG_C + c;
            const size_t base10 = ((size_t)(yi1 * IMG_W + xi0)) * IMG_C + c;
            const size_t base11 = ((size_t)(yi1 * IMG_W + xi1)) * IMG_C + c;

            const fvec4 v00 = *reinterpret_cast<const fvec4*>(img + base00);
            const fvec4 v01 = *reinterpret_cast<const fvec4*>(img + base01);
            const fvec4 v10 = *reinterpret_cast<const fvec4*>(img + base10);
            const fvec4 v11 = *reinterpret_cast<const fvec4*>(img + base11);

            const fvec4 top = v00 + (v01 - v00) * fx;
            const fvec4 bot = v10 + (v11 - v10) * fx;
            const fvec4 o   = top + (bot - top) * fy;

            const int r = roibase + rl;
            const size_t obase = ((size_t)(r * CELLS + cell)) * IMG_C + c;
            __builtin_nontemporal_store(o, reinterpret_cast<fvec4*>(out + obase));
        }
    }
}

extern "C" void kernel_launch(void* const* d_in, const int* in_sizes, int n_in,
                              void* d_out, int out_size, void* d_ws, size_t ws_size,
                              hipStream_t stream) {
    const float* img  = (const float*)d_in[0];
    const int*   rois = (const int*)d_in[1];
    float*       out  = (float*)d_out;

    const int nblocks = (NROIS / RPB) * NSLAB;  // 2048 blocks, 256 threads
    roi_pool_kernel<<<nblocks, 256, 0, stream>>>(img, rois, out);
}